// Round 1
// baseline (489.514 us; speedup 1.0000x reference)
//
#include <hip/hip_runtime.h>
#include <math.h>

// Problem constants (from reference): B=16, D=64, H=160, W=320, T=20
#define BDIM 16
#define DDIM 64
#define TDIM 20
#define NDIM (160*320)   // 51200 spatial positions

// ---- Kernel 1: per-chunk online-softmax stats over the spatial axis ----
// grid = (NB, B), block = 256. Each thread owns 4 consecutive n (float4 loads).
constexpr int K1_THREADS = 256;
constexpr int K1_NPT     = 4;
constexpr int K1_CHUNK   = K1_THREADS * K1_NPT;   // 1024
constexpr int K1_NB      = NDIM / K1_CHUNK;       // 50 (exact)

__global__ __launch_bounds__(K1_THREADS)
void k_stats(const float* __restrict__ x1,
             const float* __restrict__ tok,      // [T, D]
             float* __restrict__ pstats)         // [NB][B][T][2] = (M, S)
{
    const int b   = blockIdx.y;
    const int nb  = blockIdx.x;
    const int tid = threadIdx.x;
    const int n0  = nb * K1_CHUNK + tid * 4;
    const float* xb = x1 + (size_t)b * DDIM * NDIM + n0;

    float acc[TDIM][4];
#pragma unroll
    for (int t = 0; t < TDIM; ++t)
        acc[t][0] = acc[t][1] = acc[t][2] = acc[t][3] = 0.f;

    // scores_t[n..n+3] = sum_d x1[d] * tok[t][d]; tok index is wave-uniform -> s_load
#pragma unroll 4
    for (int d = 0; d < DDIM; ++d) {
        const float4 v = *(const float4*)(xb + (size_t)d * NDIM);
#pragma unroll
        for (int t = 0; t < TDIM; ++t) {
            const float tk = tok[t * DDIM + d];
            acc[t][0] = fmaf(v.x, tk, acc[t][0]);
            acc[t][1] = fmaf(v.y, tk, acc[t][1]);
            acc[t][2] = fmaf(v.z, tk, acc[t][2]);
            acc[t][3] = fmaf(v.w, tk, acc[t][3]);
        }
    }

    // per-thread softmax stats over its 4 n's
    float m[TDIM], s[TDIM];
#pragma unroll
    for (int t = 0; t < TDIM; ++t) {
        const float mm = fmaxf(fmaxf(acc[t][0], acc[t][1]),
                               fmaxf(acc[t][2], acc[t][3]));
        m[t] = mm;
        s[t] = __expf(acc[t][0] - mm) + __expf(acc[t][1] - mm) +
               __expf(acc[t][2] - mm) + __expf(acc[t][3] - mm);
    }

    // wave64 butterfly merge of (m,s) per t
#pragma unroll
    for (int t = 0; t < TDIM; ++t) {
        float mm = m[t], ss = s[t];
        for (int off = 32; off; off >>= 1) {
            const float m2 = __shfl_xor(mm, off);
            const float s2 = __shfl_xor(ss, off);
            const float mx = fmaxf(mm, m2);
            ss = ss * __expf(mm - mx) + s2 * __expf(m2 - mx);
            mm = mx;
        }
        m[t] = mm; s[t] = ss;
    }

    // cross-wave merge (4 waves) via LDS
    __shared__ float red[4][TDIM][2];
    const int wave = tid >> 6;
    const int lane = tid & 63;
    if (lane == 0) {
#pragma unroll
        for (int t = 0; t < TDIM; ++t) {
            red[wave][t][0] = m[t];
            red[wave][t][1] = s[t];
        }
    }
    __syncthreads();
    if (tid < TDIM) {
        float mm = red[0][tid][0], ss = red[0][tid][1];
#pragma unroll
        for (int w = 1; w < 4; ++w) {
            const float m2 = red[w][tid][0], s2 = red[w][tid][1];
            const float mx = fmaxf(mm, m2);
            ss = ss * __expf(mm - mx) + s2 * __expf(m2 - mx);
            mm = mx;
        }
        float* o = pstats + ((size_t)(nb * BDIM + b) * TDIM + tid) * 2;
        o[0] = mm;
        o[1] = ss;
    }
}

// ---- Kernel 2: merge the NB partials per (b,t); fold mask & count into C ----
__global__ void k_merge(const float* __restrict__ pstats,
                        const int* __restrict__ mask,   // [T]
                        float* __restrict__ stats)      // [B][T][2] = (M, C)
{
    const int i = threadIdx.x;
    if (i >= BDIM * TDIM) return;
    const int b = i / TDIM;
    const int t = i % TDIM;

    float mm = -INFINITY, ss = 0.f;
    for (int nb = 0; nb < K1_NB; ++nb) {
        const float* p = pstats + ((size_t)(nb * BDIM + b) * TDIM + t) * 2;
        const float m2 = p[0], s2 = p[1];
        const float mx = fmaxf(mm, m2);
        ss = ss * __expf(mm - mx) + s2 * __expf(m2 - mx);
        mm = mx;
    }
    float cnt = 0.f;
#pragma unroll
    for (int tt = 0; tt < TDIM; ++tt) cnt += (float)mask[tt];
    const float c = (float)mask[t] / (ss * cnt);
    stats[(b * TDIM + t) * 2 + 0] = mm;
    stats[(b * TDIM + t) * 2 + 1] = c;
}

// ---- Kernel 3: recompute scores, form weight, scale & write out ----
// grid = (N/256, B), block = 256; one n per thread, x1 column held in registers.
__global__ __launch_bounds__(256)
void k_out(const float* __restrict__ x1,
           const float* __restrict__ tok,
           const float* __restrict__ stats,   // [B][T][2] = (M, C)
           float* __restrict__ out)
{
    const int b = blockIdx.y;
    const int n = blockIdx.x * 256 + threadIdx.x;
    const size_t base = (size_t)b * DDIM * NDIM + n;

    float v[DDIM];
#pragma unroll
    for (int d = 0; d < DDIM; ++d)
        v[d] = x1[base + (size_t)d * NDIM];

    float acc[TDIM];
#pragma unroll
    for (int t = 0; t < TDIM; ++t) acc[t] = 0.f;

#pragma unroll 8
    for (int d = 0; d < DDIM; ++d) {
        const float vd = v[d];
#pragma unroll
        for (int t = 0; t < TDIM; ++t)
            acc[t] = fmaf(vd, tok[t * DDIM + d], acc[t]);
    }

    float w = 0.f;
#pragma unroll
    for (int t = 0; t < TDIM; ++t) {
        const float M = stats[(b * TDIM + t) * 2 + 0];   // wave-uniform -> s_load
        const float C = stats[(b * TDIM + t) * 2 + 1];
        w = fmaf(__expf(acc[t] - M), C, w);
    }

#pragma unroll
    for (int d = 0; d < DDIM; ++d)
        out[base + (size_t)d * NDIM] = v[d] * w;
}

extern "C" void kernel_launch(void* const* d_in, const int* in_sizes, int n_in,
                              void* d_out, int out_size, void* d_ws, size_t ws_size,
                              hipStream_t stream)
{
    const float* x1   = (const float*)d_in[0];   // [B, D, H, W]
    const float* x2   = (const float*)d_in[1];   // [1, T, D]
    const int*   mask = (const int*)d_in[2];     // [1, T]
    float* out = (float*)d_out;

    float* pstats = (float*)d_ws;                                   // NB*B*T*2 floats (128 KB)
    float* stats  = pstats + (size_t)K1_NB * BDIM * TDIM * 2;       // B*T*2 floats

    k_stats<<<dim3(K1_NB, BDIM), K1_THREADS, 0, stream>>>(x1, x2, pstats);
    k_merge<<<1, 320, 0, stream>>>(pstats, mask, stats);
    k_out<<<dim3(NDIM / 256, BDIM), 256, 0, stream>>>(x1, x2, stats, out);
}

// Round 2
// 488.124 us; speedup vs baseline: 1.0028x; 1.0028x over previous
//
#include <hip/hip_runtime.h>
#include <math.h>

// Problem constants (from reference): B=16, D=64, H=160, W=320, T=20
#define BDIM 16
#define DDIM 64
#define TDIM 20
#define NDIM (160*320)   // 51200 spatial positions

#define NEG_HUGE (-3.402823466e38f)

// ---- Kernel 1: per-chunk online-softmax stats over the spatial axis ----
// grid = (NB, B), block = 256. Each thread owns 4 consecutive n (float4 loads).
constexpr int K1_THREADS = 256;
constexpr int K1_NPT     = 4;
constexpr int K1_CHUNK   = K1_THREADS * K1_NPT;   // 1024
constexpr int K1_NB      = NDIM / K1_CHUNK;       // 50 (exact)

__global__ __launch_bounds__(K1_THREADS)
void k_stats(const float* __restrict__ x1,
             const float* __restrict__ tok,      // [T, D]
             float* __restrict__ pstats)         // [NB][B][T][2] = (M, S)
{
    const int b   = blockIdx.y;
    const int nb  = blockIdx.x;
    const int tid = threadIdx.x;
    const int n0  = nb * K1_CHUNK + tid * 4;
    const float* xb = x1 + (size_t)b * DDIM * NDIM + n0;

    float acc[TDIM][4];
#pragma unroll
    for (int t = 0; t < TDIM; ++t)
        acc[t][0] = acc[t][1] = acc[t][2] = acc[t][3] = 0.f;

    // scores_t[n..n+3] = sum_d x1[d] * tok[t][d]; tok index is wave-uniform -> s_load
#pragma unroll 4
    for (int d = 0; d < DDIM; ++d) {
        const float4 v = *(const float4*)(xb + (size_t)d * NDIM);
#pragma unroll
        for (int t = 0; t < TDIM; ++t) {
            const float tk = tok[t * DDIM + d];
            acc[t][0] = fmaf(v.x, tk, acc[t][0]);
            acc[t][1] = fmaf(v.y, tk, acc[t][1]);
            acc[t][2] = fmaf(v.z, tk, acc[t][2]);
            acc[t][3] = fmaf(v.w, tk, acc[t][3]);
        }
    }

    // per-thread softmax stats over its 4 n's
    float m[TDIM], s[TDIM];
#pragma unroll
    for (int t = 0; t < TDIM; ++t) {
        const float mm = fmaxf(fmaxf(acc[t][0], acc[t][1]),
                               fmaxf(acc[t][2], acc[t][3]));
        m[t] = mm;
        s[t] = __expf(acc[t][0] - mm) + __expf(acc[t][1] - mm) +
               __expf(acc[t][2] - mm) + __expf(acc[t][3] - mm);
    }

    // wave64 butterfly merge of (m,s) per t
#pragma unroll
    for (int t = 0; t < TDIM; ++t) {
        float mm = m[t], ss = s[t];
        for (int off = 32; off; off >>= 1) {
            const float m2 = __shfl_xor(mm, off);
            const float s2 = __shfl_xor(ss, off);
            const float mx = fmaxf(mm, m2);
            ss = ss * __expf(mm - mx) + s2 * __expf(m2 - mx);
            mm = mx;
        }
        m[t] = mm; s[t] = ss;
    }

    // cross-wave merge (4 waves) via LDS
    __shared__ float red[4][TDIM][2];
    const int wave = tid >> 6;
    const int lane = tid & 63;
    if (lane == 0) {
#pragma unroll
        for (int t = 0; t < TDIM; ++t) {
            red[wave][t][0] = m[t];
            red[wave][t][1] = s[t];
        }
    }
    __syncthreads();
    if (tid < TDIM) {
        float mm = red[0][tid][0], ss = red[0][tid][1];
#pragma unroll
        for (int w = 1; w < 4; ++w) {
            const float m2 = red[w][tid][0], s2 = red[w][tid][1];
            const float mx = fmaxf(mm, m2);
            ss = ss * __expf(mm - mx) + s2 * __expf(m2 - mx);
            mm = mx;
        }
        float* o = pstats + ((size_t)(nb * BDIM + b) * TDIM + tid) * 2;
        o[0] = mm;
        o[1] = ss;
    }
}

// ---- Kernel 2: merge the NB partials per (b,t) in parallel ----
// grid = (B, T), block = 64 (one wave). Lane l owns chunk l (NB=50 <= 64).
__global__ __launch_bounds__(64)
void k_merge(const float* __restrict__ pstats,
             const int* __restrict__ mask,   // [T]
             float* __restrict__ stats)      // [B][T][2] = (M, C)
{
    const int b = blockIdx.x;
    const int t = blockIdx.y;
    const int l = threadIdx.x;

    float mm = NEG_HUGE, ss = 0.f;
    if (l < K1_NB) {
        const float* p = pstats + ((size_t)(l * BDIM + b) * TDIM + t) * 2;
        mm = p[0];
        ss = p[1];
    }
    // butterfly merge across the wave; identity (NEG_HUGE, 0) is absorbing:
    // exp(NEG_HUGE - finite) underflows to 0, exp(0)=1 keeps real partials.
    for (int off = 32; off; off >>= 1) {
        const float m2 = __shfl_xor(mm, off);
        const float s2 = __shfl_xor(ss, off);
        const float mx = fmaxf(mm, m2);
        ss = ss * __expf(mm - mx) + s2 * __expf(m2 - mx);
        mm = mx;
    }
    if (l == 0) {
        float cnt = 0.f;
#pragma unroll
        for (int tt = 0; tt < TDIM; ++tt) cnt += (float)mask[tt];
        const float c = (float)mask[t] / (ss * cnt);
        stats[(b * TDIM + t) * 2 + 0] = mm;
        stats[(b * TDIM + t) * 2 + 1] = c;
    }
}

// ---- Kernel 3: recompute scores, form weight, scale & write out ----
// grid = (N/1024, B), block = 256; each thread owns 4 consecutive n (float4).
// Explicit two-pass: pass 1 computes the weight, pass 2 re-loads x1 (L2/L3-hot)
// and writes out. Compiler barrier between passes prevents CSE of the loads
// (which would re-create a 256-float live array -> scratch spills).
__global__ __launch_bounds__(256)
void k_out(const float* __restrict__ x1,
           const float* __restrict__ tok,
           const float* __restrict__ stats,   // [B][T][2] = (M, C)
           float* __restrict__ out)
{
    const int b  = blockIdx.y;
    const int n0 = (blockIdx.x * 256 + threadIdx.x) * 4;
    const size_t base = (size_t)b * DDIM * NDIM + n0;

    float acc[TDIM][4];
#pragma unroll
    for (int t = 0; t < TDIM; ++t)
        acc[t][0] = acc[t][1] = acc[t][2] = acc[t][3] = 0.f;

#pragma unroll 4
    for (int d = 0; d < DDIM; ++d) {
        const float4 v = *(const float4*)(x1 + base + (size_t)d * NDIM);
#pragma unroll
        for (int t = 0; t < TDIM; ++t) {
            const float tk = tok[t * DDIM + d];
            acc[t][0] = fmaf(v.x, tk, acc[t][0]);
            acc[t][1] = fmaf(v.y, tk, acc[t][1]);
            acc[t][2] = fmaf(v.z, tk, acc[t][2]);
            acc[t][3] = fmaf(v.w, tk, acc[t][3]);
        }
    }

    float w0 = 0.f, w1 = 0.f, w2 = 0.f, w3 = 0.f;
#pragma unroll
    for (int t = 0; t < TDIM; ++t) {
        const float M = stats[(b * TDIM + t) * 2 + 0];   // wave-uniform -> s_load
        const float C = stats[(b * TDIM + t) * 2 + 1];
        w0 = fmaf(__expf(acc[t][0] - M), C, w0);
        w1 = fmaf(__expf(acc[t][1] - M), C, w1);
        w2 = fmaf(__expf(acc[t][2] - M), C, w2);
        w3 = fmaf(__expf(acc[t][3] - M), C, w3);
    }

    // prevent the compiler from CSE-ing pass-2 loads with pass-1 loads
    __asm__ __volatile__("" ::: "memory");

#pragma unroll 4
    for (int d = 0; d < DDIM; ++d) {
        float4 v = *(const float4*)(x1 + base + (size_t)d * NDIM);
        v.x *= w0; v.y *= w1; v.z *= w2; v.w *= w3;
        *(float4*)(out + base + (size_t)d * NDIM) = v;
    }
}

extern "C" void kernel_launch(void* const* d_in, const int* in_sizes, int n_in,
                              void* d_out, int out_size, void* d_ws, size_t ws_size,
                              hipStream_t stream)
{
    const float* x1   = (const float*)d_in[0];   // [B, D, H, W]
    const float* x2   = (const float*)d_in[1];   // [1, T, D]
    const int*   mask = (const int*)d_in[2];     // [1, T]
    float* out = (float*)d_out;

    float* pstats = (float*)d_ws;                                   // NB*B*T*2 floats (128 KB)
    float* stats  = pstats + (size_t)K1_NB * BDIM * TDIM * 2;       // B*T*2 floats

    k_stats<<<dim3(K1_NB, BDIM), K1_THREADS, 0, stream>>>(x1, x2, pstats);
    k_merge<<<dim3(BDIM, TDIM), 64, 0, stream>>>(pstats, mask, stats);
    k_out<<<dim3(NDIM / 1024, BDIM), 256, 0, stream>>>(x1, x2, stats, out);
}